// Round 4
// baseline (738.810 us; speedup 1.0000x reference)
//
#include <hip/hip_runtime.h>
#include <hip/hip_bf16.h>

// Problem constants: T=1024, B=64, I=512, H=512, L=2. 4H=2048. K=512.
#define T_DIM 1024
#define B_DIM 64
#define H_DIM 512

typedef __attribute__((ext_vector_type(8))) short short8;
typedef __attribute__((ext_vector_type(4))) float f32x4;

typedef __attribute__((address_space(3))) void lds_void_t;
typedef __attribute__((address_space(1))) void glob_void_t;

static __device__ __forceinline__ unsigned short f2b_rne(float f) {
  unsigned u = __float_as_uint(f);
  u += 0x7fffu + ((u >> 16) & 1u);
  return (unsigned short)(u >> 16);
}

static __device__ __forceinline__ float sigm(float x) {
  return 1.0f / (1.0f + __expf(-x));
}
// NaN-safe fast tanh: uses |x| so exp never produces inf-inf.
static __device__ __forceinline__ float tanh_fast(float x) {
  float e = __expf(2.0f * fabsf(x));
  float t = 1.0f - 2.0f / (e + 1.0f);
  return copysignf(t, x);
}

// ---------------- fp32 -> bf16 conversion (vectorized x4, grid-stride) ------
__global__ void conv_f2b(const float* __restrict__ in,
                         unsigned short* __restrict__ out, int n4) {
  int idx = blockIdx.x * blockDim.x + threadIdx.x;
  int stride = gridDim.x * blockDim.x;
  for (int i = idx; i < n4; i += stride) {
    float4 v = reinterpret_cast<const float4*>(in)[i];
    ushort4 o;
    o.x = f2b_rne(v.x); o.y = f2b_rne(v.y);
    o.z = f2b_rne(v.z); o.w = f2b_rne(v.w);
    reinterpret_cast<ushort4*>(out)[i] = o;
  }
}

// ---------------- hhb[l][b][g] = b_ih[g] + b_hh[g] + h0[l,b,:] . w_hh[g,:] ---
__global__ void hh_bias(const float* __restrict__ h0,
                        const float* __restrict__ whh0, const float* __restrict__ whh1,
                        const float* __restrict__ bih0, const float* __restrict__ bhh0,
                        const float* __restrict__ bih1, const float* __restrict__ bhh1,
                        float* __restrict__ hhb) {
  const int l = blockIdx.y;
  const int wid = threadIdx.x >> 6;
  const int lane = threadIdx.x & 63;
  const int g = blockIdx.x * 4 + wid;  // 0..2047
  const float* wh = l ? whh1 : whh0;
  const float* bi = l ? bih1 : bih0;
  const float* bh = l ? bhh1 : bhh0;
  const float4* wr = reinterpret_cast<const float4*>(wh + (size_t)g * H_DIM);
  float4 w0 = wr[lane * 2];
  float4 w1 = wr[lane * 2 + 1];
  float bias = bi[g] + bh[g];
  const float* h0l = h0 + (size_t)l * B_DIM * H_DIM;
  for (int b = 0; b < B_DIM; ++b) {
    const float4* hr = reinterpret_cast<const float4*>(h0l + (size_t)b * H_DIM);
    float4 a0 = hr[lane * 2];
    float4 a1 = hr[lane * 2 + 1];
    float acc = a0.x * w0.x + a0.y * w0.y + a0.z * w0.z + a0.w * w0.w +
                a1.x * w1.x + a1.y * w1.y + a1.z * w1.z + a1.w * w1.w;
#pragma unroll
    for (int off = 32; off; off >>= 1) acc += __shfl_xor(acc, off);
    if (lane == 0) hhb[((size_t)l * B_DIM + b) * 2048 + g] = acc + bias;
  }
}

// ---------------- fused LSTM-layer GEMM, 256^2 8-phase (T2+T3+T4+T5) --------
// gates[m, gate*512+h] = sum_k A[m,k] * W[gate*512+h, k]   (B^T layout)
// Block tile: 256 m-rows x 64 h x 4 gates (256x256 eff). 512 thr = 8 waves 2Mx4N.
// eff col n: gate = (n>>4)&3, hsub = (n>>6)*16 + (n&15)  -> wave wn (n-quarter)
// has n-frags = the 4 gates of h-range [h0v+wn*16, +16): gate-fused epilogue.
// LDS: A/B double-buffered [2][256][64] bf16 = 128 KiB. XOR swizzle chunk^=row&7
// on global SOURCE (linear gload_lds dest) and on ds_read address.
// Schedule per K-tile (BK=64): 4 phases, 16 MFMA each; stage next K-tile's A
// halves in P0, B halves in P1 (2 gload_lds dwordx4 each); vmcnt(4) only at
// K-tile head (counted, never 0 mid-loop); raw s_barrier; setprio around MFMA.
template <int LAYER>
__global__ __launch_bounds__(512, 2) void lstm_gemm(
    const unsigned short* __restrict__ Abf,   // [65536, 512] bf16
    const unsigned short* __restrict__ Wbf,   // [2048, 512]  bf16
    const float* __restrict__ hhb,            // [64, 2048] this layer
    const float* __restrict__ c0l,            // [64, 512]  this layer
    unsigned short* __restrict__ hy_bf,       // layer0: bf16 out (ws)
    float* __restrict__ out_hy,               // layer1: fp32 out (d_out)
    float* __restrict__ out_lasth,            // [64,512] this layer
    float* __restrict__ out_lastc) {          // [64,512] this layer
  __shared__ __attribute__((aligned(16))) unsigned short Alds[2][256 * 64];
  __shared__ __attribute__((aligned(16))) unsigned short Blds[2][256 * 64];

  const int tid = threadIdx.x;               // 0..511
  const int lane = tid & 63;
  const int wid = tid >> 6;                  // 0..7
  const int wm = wid >> 2, wn = wid & 3;     // 2M x 4N
  const int lane_lo = lane & 15, lane_hi = lane >> 4;

  // XCD chunked swizzle (bijective: 2048 % 8 == 0). n fastest -> the 8
  // sharers of one A-panel are consecutive -> same XCD L2.
  const int lin = blockIdx.x;
  const int wg = (lin & 7) * 256 + (lin >> 3);
  const int bn = wg & 7;     // n-tile (8)
  const int bm = wg >> 3;    // m-tile (256)
  const int m0 = bm * 256;
  const int h0v = bn * 64;

  // ---- staging thread mapping: thread t, round r covers LDS linear 16B slot
  // (r*512+t); row-in-half = r*64 + (t>>3), slot = t&7. row&7 == (t>>3)&7.
  const int rowh = tid >> 3;                 // 0..63
  const int slot = tid & 7;
  const int csch = slot ^ (rowh & 7);        // swizzled source chunk (const)

  // A source: global row m0 + ha*128 + r*64 + rowh, chunk csch
  const unsigned short* pA = Abf + (size_t)(m0 + rowh) * 512 + csch * 8;
  // B source: eff row n = hb*128 + r*64 + rowh ->
  //   gate = rowh>>4, hsub = (hb*2+r)*16 + (rowh&15)
  const unsigned short* pB =
      Wbf + (size_t)((rowh >> 4) * 512 + h0v + (rowh & 15)) * 512 + csch * 8;

  char* aldsB = (char*)&Alds[0][0];
  char* bldsB = (char*)&Blds[0][0];
  const int dstBase = wid * 1024;  // + bb*32768 + ha*16384 + r*8192 (bytes)

#define STAGE_A(bb, kt, ha)                                                   \
  {                                                                           \
    __builtin_amdgcn_global_load_lds(                                         \
        (const glob_void_t*)(pA + (size_t)(ha)*65536 + (kt)*64),              \
        (lds_void_t*)(aldsB + (bb)*32768 + (ha)*16384 + dstBase), 16, 0, 0);  \
    __builtin_amdgcn_global_load_lds(                                         \
        (const glob_void_t*)(pA + (size_t)(ha)*65536 + 32768 + (kt)*64),      \
        (lds_void_t*)(aldsB + (bb)*32768 + (ha)*16384 + 8192 + dstBase), 16,  \
        0, 0);                                                                \
  }
#define STAGE_B(bb, kt, hb)                                                   \
  {                                                                           \
    __builtin_amdgcn_global_load_lds(                                         \
        (const glob_void_t*)(pB + (size_t)((hb)*2) * 8192 + (kt)*64),         \
        (lds_void_t*)(bldsB + (bb)*32768 + (hb)*16384 + dstBase), 16, 0, 0);  \
    __builtin_amdgcn_global_load_lds(                                         \
        (const glob_void_t*)(pB + (size_t)((hb)*2 + 1) * 8192 + (kt)*64),     \
        (lds_void_t*)(bldsB + (bb)*32768 + (hb)*16384 + 8192 + dstBase), 16,  \
        0, 0);                                                                \
  }

  // ---- compute-side LDS read offsets (bytes). row&7 == lane_lo&7 for both.
  int cx0 = ((0 * 4 + lane_hi) ^ (lane_lo & 7)) << 4;  // kk=0 chunk byte
  int cx1 = ((1 * 4 + lane_hi) ^ (lane_lo & 7)) << 4;  // kk=1
  const int aRow = (wm * 128 + lane_lo) * 128;
  const int bRow = (wn * 64 + lane_lo) * 128;
#define A_ADDR(bb, r, cx) (aldsB + (bb)*32768 + aRow + (r)*2048 + (cx))
#define B_ADDR(bb, g, cx) (bldsB + (bb)*32768 + bRow + (g)*2048 + (cx))
#define LD8(p) (*reinterpret_cast<const short8*>(p))

  f32x4 acc[8][4] = {};
  short8 aF[4][2], bF[2][2];

  // ---- prologue: stage K-tile 0 into buffer 0 (8 loads)
  STAGE_A(0, 0, 0); STAGE_A(0, 0, 1);
  STAGE_B(0, 0, 0); STAGE_B(0, 0, 1);

#pragma unroll
  for (int kt = 0; kt < 8; ++kt) {
    const int cur = kt & 1, nxt = cur ^ 1;
    // ---------------- phase 0: stage A(kt+1); wait kt's 8 loads; MFMA m0-3 x g0-1
    if (kt < 7) { STAGE_A(nxt, kt + 1, 0); STAGE_A(nxt, kt + 1, 1); }
    if (kt < 7) {
      asm volatile("s_waitcnt vmcnt(4)" ::: "memory");
    } else {
      asm volatile("s_waitcnt vmcnt(0)" ::: "memory");
    }
    __builtin_amdgcn_s_barrier();
#pragma unroll
    for (int r = 0; r < 4; ++r) {
      aF[r][0] = LD8(A_ADDR(cur, r, cx0));
      aF[r][1] = LD8(A_ADDR(cur, r, cx1));
    }
#pragma unroll
    for (int g = 0; g < 2; ++g) {
      bF[g][0] = LD8(B_ADDR(cur, g, cx0));
      bF[g][1] = LD8(B_ADDR(cur, g, cx1));
    }
    __builtin_amdgcn_s_barrier();
    __builtin_amdgcn_s_setprio(1);
#pragma unroll
    for (int r = 0; r < 4; ++r)
#pragma unroll
      for (int g = 0; g < 2; ++g) {
        acc[r][g] = __builtin_amdgcn_mfma_f32_16x16x32_bf16(aF[r][0], bF[g][0], acc[r][g], 0, 0, 0);
        acc[r][g] = __builtin_amdgcn_mfma_f32_16x16x32_bf16(aF[r][1], bF[g][1], acc[r][g], 0, 0, 0);
      }
    __builtin_amdgcn_s_setprio(0);
    // ---------------- phase 1: stage B(kt+1); MFMA m0-3 x g2-3
#pragma unroll
    for (int g = 0; g < 2; ++g) {
      bF[g][0] = LD8(B_ADDR(cur, 2 + g, cx0));
      bF[g][1] = LD8(B_ADDR(cur, 2 + g, cx1));
    }
    if (kt < 7) { STAGE_B(nxt, kt + 1, 0); STAGE_B(nxt, kt + 1, 1); }
    __builtin_amdgcn_s_barrier();
    __builtin_amdgcn_s_setprio(1);
#pragma unroll
    for (int r = 0; r < 4; ++r)
#pragma unroll
      for (int g = 0; g < 2; ++g) {
        acc[r][2 + g] = __builtin_amdgcn_mfma_f32_16x16x32_bf16(aF[r][0], bF[g][0], acc[r][2 + g], 0, 0, 0);
        acc[r][2 + g] = __builtin_amdgcn_mfma_f32_16x16x32_bf16(aF[r][1], bF[g][1], acc[r][2 + g], 0, 0, 0);
      }
    __builtin_amdgcn_s_setprio(0);
    // ---------------- phase 2: MFMA m4-7 x g0-1
#pragma unroll
    for (int r = 0; r < 4; ++r) {
      aF[r][0] = LD8(A_ADDR(cur, 4 + r, cx0));
      aF[r][1] = LD8(A_ADDR(cur, 4 + r, cx1));
    }
#pragma unroll
    for (int g = 0; g < 2; ++g) {
      bF[g][0] = LD8(B_ADDR(cur, g, cx0));
      bF[g][1] = LD8(B_ADDR(cur, g, cx1));
    }
    __builtin_amdgcn_s_barrier();
    __builtin_amdgcn_s_setprio(1);
#pragma unroll
    for (int r = 0; r < 4; ++r)
#pragma unroll
      for (int g = 0; g < 2; ++g) {
        acc[4 + r][g] = __builtin_amdgcn_mfma_f32_16x16x32_bf16(aF[r][0], bF[g][0], acc[4 + r][g], 0, 0, 0);
        acc[4 + r][g] = __builtin_amdgcn_mfma_f32_16x16x32_bf16(aF[r][1], bF[g][1], acc[4 + r][g], 0, 0, 0);
      }
    __builtin_amdgcn_s_setprio(0);
    // ---------------- phase 3: MFMA m4-7 x g2-3
#pragma unroll
    for (int g = 0; g < 2; ++g) {
      bF[g][0] = LD8(B_ADDR(cur, 2 + g, cx0));
      bF[g][1] = LD8(B_ADDR(cur, 2 + g, cx1));
    }
    __builtin_amdgcn_s_barrier();
    __builtin_amdgcn_s_setprio(1);
#pragma unroll
    for (int r = 0; r < 4; ++r)
#pragma unroll
      for (int g = 0; g < 2; ++g) {
        acc[4 + r][2 + g] = __builtin_amdgcn_mfma_f32_16x16x32_bf16(aF[r][0], bF[g][0], acc[4 + r][2 + g], 0, 0, 0);
        acc[4 + r][2 + g] = __builtin_amdgcn_mfma_f32_16x16x32_bf16(aF[r][1], bF[g][1], acc[4 + r][2 + g], 0, 0, 0);
      }
    __builtin_amdgcn_s_setprio(0);
    __builtin_amdgcn_s_barrier();  // all reads of buf[cur] done before kt+1 stages into it
  }

  // ---- fused gate epilogue: fragment index IS the gate
  const int h = h0v + wn * 16 + lane_lo;
#pragma unroll
  for (int r = 0; r < 8; ++r) {
#pragma unroll
    for (int j = 0; j < 4; ++j) {
      int m = m0 + wm * 128 + r * 16 + lane_hi * 4 + j;
      int b = m & (B_DIM - 1);
      bool isLast = (m >> 6) == (T_DIM - 1);
      const float* hb = hhb + (size_t)b * 2048;
      float gi = acc[r][0][j] + hb[h];
      float gf = acc[r][1][j] + hb[512 + h];
      float gg = acc[r][2][j] + hb[1024 + h];
      float go = acc[r][3][j] + hb[1536 + h];
      float iv = sigm(gi), fv = sigm(gf), gv = tanh_fast(gg), ov = sigm(go);
      float cv = fv * c0l[b * H_DIM + h] + iv * gv;
      float hv = ov * tanh_fast(cv);
      if (LAYER == 0) {
        hy_bf[(size_t)m * H_DIM + h] = f2b_rne(hv);
      } else {
        out_hy[(size_t)m * H_DIM + h] = hv;
      }
      if (isLast) {
        out_lasth[b * H_DIM + h] = hv;
        out_lastc[b * H_DIM + h] = cv;
      }
    }
  }
#undef STAGE_A
#undef STAGE_B
#undef A_ADDR
#undef B_ADDR
#undef LD8
}

extern "C" void kernel_launch(void* const* d_in, const int* in_sizes, int n_in,
                              void* d_out, int out_size, void* d_ws, size_t ws_size,
                              hipStream_t stream) {
  const float* x    = (const float*)d_in[0];
  const float* h0   = (const float*)d_in[1];
  const float* c0   = (const float*)d_in[2];
  const float* wih0 = (const float*)d_in[3];
  const float* whh0 = (const float*)d_in[4];
  const float* bih0 = (const float*)d_in[5];
  const float* bhh0 = (const float*)d_in[6];
  const float* wih1 = (const float*)d_in[7];
  const float* whh1 = (const float*)d_in[8];
  const float* bih1 = (const float*)d_in[9];
  const float* bhh1 = (const float*)d_in[10];
  float* out = (float*)d_out;

  // workspace layout (bytes)
  char* ws = (char*)d_ws;
  unsigned short* x_bf   = (unsigned short*)(ws);              // 67108864 B
  unsigned short* hy0_bf = (unsigned short*)(ws + 67108864);   // 67108864 B
  unsigned short* w0_bf  = (unsigned short*)(ws + 134217728);  // 2097152 B
  unsigned short* w1_bf  = (unsigned short*)(ws + 136314880);  // 2097152 B
  float*          hhb    = (float*)(ws + 138412032);           // 1048576 B

  conv_f2b<<<2048, 256, 0, stream>>>(x, x_bf, 33554432 / 4);
  conv_f2b<<<512, 256, 0, stream>>>(wih0, w0_bf, 1048576 / 4);
  conv_f2b<<<512, 256, 0, stream>>>(wih1, w1_bf, 1048576 / 4);
  hh_bias<<<dim3(512, 2), 256, 0, stream>>>(h0, whh0, whh1, bih0, bhh0, bih1, bhh1, hhb);

  float* res   = out;                         // [65536, 512]
  float* lasth = out + 33554432;              // [2, 64, 512]
  float* lastc = out + 33554432 + 65536;      // [2, 64, 512]

  lstm_gemm<0><<<2048, 512, 0, stream>>>(
      x_bf, w0_bf, hhb, c0, hy0_bf, nullptr, lasth, lastc);
  lstm_gemm<1><<<2048, 512, 0, stream>>>(
      hy0_bf, w1_bf, hhb + 64 * 2048, c0 + 64 * 512, nullptr, res,
      lasth + 64 * 512, lastc + 64 * 512);
}